// Round 2
// baseline (90.741 us; speedup 1.0000x reference)
//
#include <hip/hip_runtime.h>

// SeparateLoss reduces algebraically:
//   mean(mask * simi) = 2 * dot(S0, S1) / N^2
// where S0/S1 = sums of L2-normalized feature rows with label 0/1.
// N = 4*64*64 = 16384 rows, C = 64 channels, nearest-resize = stride-2 pick.
//
// Single fused kernel: 256 blocks compute per-block partial sums, publish
// them with a release-flag per block (NO zero-init needed: flags start at
// harness poison 0xAAAAAAAA != MAGIC on every call), and block 255
// spin-acquires all flags then does the final reduction + dot. This saves
// one kernel dispatch vs the two-kernel version (launch-overhead regime).

#define H 128
#define W 128
#define C 64
#define OSIZE 64
#define NROWS (4 * OSIZE * OSIZE) // 16384
#define NBLK 256                  // 4 batches * 64 output rows
#define MAGIC 0x5ca1ab1e

__global__ __launch_bounds__(256) void separate_loss_fused(
    const float* __restrict__ feat,   // [4][64][128][128]
    const int*   __restrict__ label,  // [4][1][128][128]
    float*       __restrict__ partials, // [NBLK][128] in ws
    int*         __restrict__ flags,    // [NBLK] in ws (poisoned, never zeroed)
    float*       __restrict__ out) {

    __shared__ float tile[C][OSIZE + 1]; // +1 pad: all phases <=2-way (free)
    __shared__ float linv[OSIZE];
    __shared__ int   lab[OSIZE];
    __shared__ float p0[4][C];
    __shared__ float p1[4][C];
    __shared__ float S[128];

    const int blk = blockIdx.x;   // 0..255
    const int b   = blk >> 6;     // batch 0..3
    const int i   = blk & 63;     // output row -> input row 2*i
    const int t   = threadIdx.x;
    const int q   = t >> 6;       // wave id 0..3

    // --- Stage feat[b][c][2i][0..127:2] into LDS via float4 (keep .x,.z).
    // 8 float4 loads/thread; each wave's 64 lanes cover 2 channels' rows
    // contiguously -> coalesced 512B segments.
    const float* frow = feat + ((size_t)(b * C) * H + 2 * i) * W;
    #pragma unroll
    for (int r = 0; r < 8; ++r) {
        const int idx = t + 256 * r;
        const int c = idx >> 5;      // 0..63
        const int u = idx & 31;      // float4 index within the 128-col row
        const float4 v = ((const float4*)(frow + (size_t)c * H * W))[u];
        tile[c][2 * u]     = v.x;    // col 4u   (even)
        tile[c][2 * u + 1] = v.z;    // col 4u+2 (even)
    }
    __syncthreads();

    // --- Per-row (j) inverse norm; lanes t<64 read tile[c][t]: 2-way, free.
    if (t < 64) {
        float ss = 0.0f;
        #pragma unroll
        for (int c = 0; c < C; ++c) {
            const float v = tile[c][t];
            ss += v * v;
        }
        linv[t] = 1.0f / fmaxf(sqrtf(ss), 1e-12f); // torch F.normalize eps
        lab[t]  = label[(b * H + 2 * i) * W + 2 * t];
    }
    __syncthreads();

    // --- Label-split per-channel accumulation. lane = channel, wave q
    // handles j in [16q, 16q+16). tile[c][jj] across lanes: 2-way, free.
    {
        const int c = t & 63;
        float s0 = 0.0f, s1 = 0.0f;
        #pragma unroll
        for (int k = 0; k < 16; ++k) {
            const int jj = q * 16 + k;
            const float v = tile[c][jj] * linv[jj];
            if (lab[jj] == 0) s0 += v; else s1 += v;
        }
        p0[q][c] = s0;
        p1[q][c] = s1;
    }
    __syncthreads();

    if (t < 64) {
        partials[blk * 128 + t]      = p0[0][t] + p0[1][t] + p0[2][t] + p0[3][t];
        partials[blk * 128 + 64 + t] = p1[0][t] + p1[1][t] + p1[2][t] + p1[3][t];
    }

    // --- Publish: device-scope release of this block's flag.
    __syncthreads();
    __threadfence();   // flush this block's partials to device scope
    __syncthreads();
    if (t == 0)
        __hip_atomic_store(&flags[blk], MAGIC, __ATOMIC_RELEASE,
                           __HIP_MEMORY_SCOPE_AGENT);

    // --- Final reduction in the last block (starts last -> shortest spin).
    if (blk != NBLK - 1) return;

    // thread t polls flag[t]; acquire semantics pull in producers' writes.
    while (__hip_atomic_load(&flags[t], __ATOMIC_ACQUIRE,
                             __HIP_MEMORY_SCOPE_AGENT) != MAGIC) { }
    __syncthreads();
    __threadfence();

    if (t < 128) {
        float s = 0.0f;
        #pragma unroll 8
        for (int k = 0; k < NBLK; ++k)
            s += partials[k * 128 + t]; // coalesced across t
        S[t] = s;
    }
    __syncthreads();
    if (t < 64) {
        float p = S[t] * S[64 + t];
        #pragma unroll
        for (int off = 32; off > 0; off >>= 1)
            p += __shfl_down(p, off, 64);
        if (t == 0)
            out[0] = 2.0f * p / ((float)NROWS * (float)NROWS);
    }
}

extern "C" void kernel_launch(void* const* d_in, const int* in_sizes, int n_in,
                              void* d_out, int out_size, void* d_ws, size_t ws_size,
                              hipStream_t stream) {
    const float* feat  = (const float*)d_in[0];
    const int*   label = (const int*)d_in[1];
    float* out      = (float*)d_out;
    float* partials = (float*)d_ws;                    // 128 KiB
    int*   flags    = (int*)((char*)d_ws + NBLK * 128 * sizeof(float)); // 1 KiB
    separate_loss_fused<<<NBLK, 256, 0, stream>>>(feat, label, partials, flags, out);
}

// Round 3
// 70.403 us; speedup vs baseline: 1.2889x; 1.2889x over previous
//
#include <hip/hip_runtime.h>

// SeparateLoss reduces algebraically:
//   mean(mask * simi) = 2 * dot(S0, S1) / N^2
// where S0/S1 = sums of L2-normalized feature rows with label 0/1.
// N = 4*64*64 = 16384 rows, C = 64 channels, nearest-resize = stride-2 pick.
//
// Two kernels (R1 structure). R2's fused spin-flag version regressed +21us:
// the cross-XCD flag handshake (acquire polls through L3 + device-scope
// release fences) costs more than one graph-serialized dispatch. Keep the
// graph dependency as the barrier.

#define H 128
#define W 128
#define C 64
#define OSIZE 64
#define NROWS (4 * OSIZE * OSIZE) // 16384
#define NBLK 256                  // 4 batches * 64 output rows

// Phase 1: one block per (b, i_out). partials[blk][0:64] = S0 part,
// partials[blk][64:128] = S1 part.
__global__ __launch_bounds__(256) void separate_loss_phase1(
    const float* __restrict__ feat,   // [4][64][128][128]
    const int*   __restrict__ label,  // [4][1][128][128]
    float*       __restrict__ partials /* [NBLK][128] */) {

    __shared__ float tile[C][OSIZE + 1]; // +1 pad: all phases <=2-way (free)
    __shared__ float linv[OSIZE];
    __shared__ int   lab[OSIZE];
    __shared__ float p0[4][C];
    __shared__ float p1[4][C];

    const int blk = blockIdx.x;   // 0..255
    const int b   = blk >> 6;     // batch 0..3
    const int i   = blk & 63;     // output row -> input row 2*i
    const int t   = threadIdx.x;
    const int q   = t >> 6;       // wave id 0..3

    // --- Stage feat[b][c][2i][0..127:2] into LDS via float4 (keep .x,.z).
    const float* frow = feat + ((size_t)(b * C) * H + 2 * i) * W;
    #pragma unroll
    for (int r = 0; r < 8; ++r) {
        const int idx = t + 256 * r;
        const int c = idx >> 5;      // 0..63
        const int u = idx & 31;      // float4 index within the 128-col row
        const float4 v = ((const float4*)(frow + (size_t)c * H * W))[u];
        tile[c][2 * u]     = v.x;    // col 4u   (even)
        tile[c][2 * u + 1] = v.z;    // col 4u+2 (even)
    }
    __syncthreads();

    // --- Per-row (j) inverse norm; lanes t<64 read tile[c][t]: 2-way, free.
    if (t < 64) {
        float ss = 0.0f;
        #pragma unroll
        for (int c = 0; c < C; ++c) {
            const float v = tile[c][t];
            ss += v * v;
        }
        linv[t] = 1.0f / fmaxf(sqrtf(ss), 1e-12f); // torch F.normalize eps
        lab[t]  = label[(b * H + 2 * i) * W + 2 * t];
    }
    __syncthreads();

    // --- Label-split per-channel accumulation. lane = channel, wave q
    // handles j in [16q, 16q+16). lab[jj] is wave-uniform -> no divergence.
    {
        const int c = t & 63;
        float s0 = 0.0f, s1 = 0.0f;
        #pragma unroll
        for (int k = 0; k < 16; ++k) {
            const int jj = q * 16 + k;
            const float v = tile[c][jj] * linv[jj];
            if (lab[jj] == 0) s0 += v; else s1 += v;
        }
        p0[q][c] = s0;
        p1[q][c] = s1;
    }
    __syncthreads();

    if (t < 64) {
        partials[blk * 128 + t]      = p0[0][t] + p0[1][t] + p0[2][t] + p0[3][t];
        partials[blk * 128 + 64 + t] = p1[0][t] + p1[1][t] + p1[2][t] + p1[3][t];
    }
}

// Phase 2: reduce partials -> S0, S1, out = 2*S0.S1/N^2.
// 256 threads: thread t covers output (t&127) over block half (t>>7),
// halving the serial loop vs the 128-thread version.
__global__ __launch_bounds__(256) void separate_loss_phase2(
    const float* __restrict__ partials, float* __restrict__ out) {
    __shared__ float Sh[2][128];
    __shared__ float S[128];
    const int t = threadIdx.x;
    const int o = t & 127;
    const int h = t >> 7;
    float s = 0.0f;
    #pragma unroll 8
    for (int k = 0; k < NBLK / 2; ++k)
        s += partials[(h * (NBLK / 2) + k) * 128 + o]; // coalesced 512B/half
    Sh[h][o] = s;
    __syncthreads();
    if (t < 128)
        S[t] = Sh[0][t] + Sh[1][t];
    __syncthreads();
    if (t < 64) {
        float p = S[t] * S[64 + t];
        #pragma unroll
        for (int off = 32; off > 0; off >>= 1)
            p += __shfl_down(p, off, 64);
        if (t == 0)
            out[0] = 2.0f * p / ((float)NROWS * (float)NROWS);
    }
}

extern "C" void kernel_launch(void* const* d_in, const int* in_sizes, int n_in,
                              void* d_out, int out_size, void* d_ws, size_t ws_size,
                              hipStream_t stream) {
    const float* feat  = (const float*)d_in[0];
    const int*   label = (const int*)d_in[1];
    float* out      = (float*)d_out;
    float* partials = (float*)d_ws; // NBLK*128*4 = 128 KiB, fully overwritten
    separate_loss_phase1<<<NBLK, 256, 0, stream>>>(feat, label, partials);
    separate_loss_phase2<<<1, 256, 0, stream>>>(partials, out);
}